// Round 4
// baseline (647.131 us; speedup 1.0000x reference)
//
#include <hip/hip_runtime.h>
#include <hip/hip_bf16.h>

// SparseMoE: N=2048, D_IN=1024, D_HID=4096, D_OUT=1024, E=8, K=2.
// R6: revert R5's asm-pinned pipeline (refuted: -47% on GEMM1, m141 failure
// mode). Back to the R4 skeleton (__syncthreads, 1-deep prefetch, XOR
// swizzle), with two changes:
//  (1) 128m x 256n tile: two B panels per block, acc[4][8], 32 MFMA/wave per
//      K-step -- amortizes the per-step barrier drain 2x and halves A-panel
//      re-fetch (16 n-blocks instead of 32). LDS 48 KB -> 3 blocks/CU.
//  (2) native __bf16 casts for fp32->bf16 packing (cvt_pk instead of 3-op
//      manual RNE), compute split in two ni-halves to cap live registers.
// GEMM2 keeps split-K=2 with plain fp32 partial stores summed in combine.

#define N_TOK   2048
#define D_IN    1024
#define D_HID   4096
#define D_OUT   1024
#define NEXP    8
#define TOPK    2
#define ROW_CAP 5120   // max padded rows: 4096 + 8*127 = 5112, round up

typedef __bf16 bf16x8 __attribute__((ext_vector_type(8)));
typedef float  f32x4  __attribute__((ext_vector_type(4)));

// native RNE casts; compiler emits v_cvt_pk_bf16_f32
__device__ inline unsigned short f2bf(float f) {
    return __builtin_bit_cast(unsigned short, (__bf16)f);
}
__device__ inline unsigned pack2(float lo, float hi) {
    unsigned short ua = __builtin_bit_cast(unsigned short, (__bf16)lo);
    unsigned short ub = __builtin_bit_cast(unsigned short, (__bf16)hi);
    return (unsigned)ua | ((unsigned)ub << 16);
}
__device__ inline void async_copy16(const void* g, void* l) {
    __builtin_amdgcn_global_load_lds(
        (const __attribute__((address_space(1))) void*)g,
        (__attribute__((address_space(3))) void*)l, 16, 0, 0);
}

// ---------------- gate: 1 wave per token ----------------
__global__ __launch_bounds__(256) void gate_kernel(
    const float* __restrict__ x, const float* __restrict__ gw,
    const float* __restrict__ gb, int* __restrict__ topi,
    float* __restrict__ topw, int* __restrict__ counts)
{
    int wave = threadIdx.x >> 6, lane = threadIdx.x & 63;
    int t = blockIdx.x * 4 + wave;
    const float* xt = x + (size_t)t * D_IN;
    float acc[NEXP];
#pragma unroll
    for (int e = 0; e < NEXP; e++) acc[e] = 0.f;
    for (int i = 0; i < D_IN / 64; i++) {
        float xv = xt[lane + 64 * i];
#pragma unroll
        for (int e = 0; e < NEXP; e++)
            acc[e] += xv * gw[e * D_IN + lane + 64 * i];
    }
#pragma unroll
    for (int e = 0; e < NEXP; e++) {
        float v = acc[e];
#pragma unroll
        for (int m = 32; m; m >>= 1) v += __shfl_xor(v, m, 64);
        acc[e] = v + gb[e];
    }
    if (lane == 0) {
        float b1v = -1e30f; int i1 = 0;
#pragma unroll
        for (int e = 0; e < NEXP; e++) if (acc[e] > b1v) { b1v = acc[e]; i1 = e; }
        float b2v = -1e30f; int i2 = 0;
#pragma unroll
        for (int e = 0; e < NEXP; e++) if (e != i1 && acc[e] > b2v) { b2v = acc[e]; i2 = e; }
        float e2 = __expf(b2v - b1v);
        float inv = 1.f / (1.f + e2);
        topi[t * 2] = i1; topi[t * 2 + 1] = i2;
        topw[t * 2] = inv; topw[t * 2 + 1] = e2 * inv;
        atomicAdd(&counts[i1], 1);
        atomicAdd(&counts[i2], 1);
    }
}

// ---------------- scan: 128-padded exclusive prefix ----------------
__global__ void scan_kernel(const int* __restrict__ counts,
                            int* __restrict__ offsets, int* __restrict__ cursor)
{
    if (threadIdx.x == 0 && blockIdx.x == 0) {
        int off = 0;
        for (int e = 0; e < NEXP; e++) {
            offsets[e] = off;
            cursor[e]  = off;
            off += (counts[e] + 127) & ~127;
        }
    }
}

// ---------------- gather: one wave per (token, k) slot ----------------
__global__ __launch_bounds__(64) void gather_kernel(
    const float* __restrict__ x, const int* __restrict__ topi,
    int* __restrict__ cursor, int* __restrict__ slot_of,
    unsigned short* __restrict__ Xe)
{
    int b = blockIdx.x;          // 0..N*TOPK-1
    int t = b >> 1;
    __shared__ int spos;
    if (threadIdx.x == 0) {
        int e = topi[b];
        int pos = atomicAdd(&cursor[e], 1);
        slot_of[b] = pos;
        spos = pos;
    }
    __syncthreads();
    int pos = spos;
    const float* src = x + (size_t)t * D_IN;
    unsigned short* dst = Xe + (size_t)pos * D_IN;
    int l = threadIdx.x;
#pragma unroll
    for (int i = 0; i < 4; i++) {
        float4 f = *(const float4*)(src + l * 4 + i * 256);
        uint2 p; p.x = pack2(f.x, f.y); p.y = pack2(f.z, f.w);
        *(uint2*)(dst + l * 4 + i * 256) = p;
    }
}

// ---------------- grouped GEMM (bf16 MFMA, fp32 weights) -------------------
// Tile 128m x 256n, BK=32, 4 waves (2m x 2n), each wave 4x8 16x16x32 MFMA.
// A: [rows, KDIM] bf16, async global_load_lds (pre-swizzled global chunk).
// Wf: [E, NDIM, KDIM] fp32, register-staged: thread t loads 16 fp32 for row
//    (t>>1) of BOTH 128-row B panels, packs to bf16, ds_writes into the
//    XOR-swizzled slots.  LDS: As 2x8 KB, Bs 2x16 KB = 48 KB.
// Swizzle: 64B row = 4x16B chunks; slot = chunk ^ ((row>>1)&3); fragment
// ds_read_b128 is 2-way bank access (free).
// 2-phase double buffer, one __syncthreads per K-step:
//   load B(t+1)->regs + issue A(t+1) DMA -> ds_read+MFMA(t) -> cvt+ds_write
//   B(t+1) -> barrier.
// OUT_MODE: 1 = bf16 store (+bias, RELU), 3 = fp32 partial store
//   (kc==0 -> Out, kc==1 -> Out2), no bias.
template <int KDIM, int NDIM, int SPLITK, bool RELU, int OUT_MODE>
__global__ __launch_bounds__(256) void moe_gemm(
    const unsigned short* __restrict__ A, const float* __restrict__ Wf,
    const float* __restrict__ bias, void* __restrict__ Out, void* __restrict__ Out2,
    const int* __restrict__ counts, const int* __restrict__ offsets)
{
    constexpr int KCHUNK = KDIM / SPLITK;
    constexpr int NSTEP  = KCHUNK / 32;
    int e  = blockIdx.z / SPLITK;
    int kc = blockIdx.z % SPLITK;
    int cnt = counts[e];
    int tm = blockIdx.y;
    if (tm * 128 >= cnt) return;
    int m0 = offsets[e] + tm * 128;
    int n0 = blockIdx.x * 256;

    __shared__ __align__(16) unsigned short As[2][128 * 32];
    __shared__ __align__(16) unsigned short Bs[2][256 * 32];

    int tid = threadIdx.x;
    int wave = tid >> 6, lane = tid & 63;

    const float* We = Wf + (size_t)e * NDIM * KDIM;

    f32x4 acc[4][8];
#pragma unroll
    for (int i = 0; i < 4; i++)
#pragma unroll
        for (int j = 0; j < 8; j++) acc[i][j] = (f32x4){0.f, 0.f, 0.f, 0.f};

    int m_off = (wave & 1) * 64;     // 2 m sub-tiles of 64
    int n_off = (wave >> 1) * 128;   // 2 n sub-tiles of 128 (one B panel each)

    // A staging (async DMA): segment s covers rows 16s..16s+15; lane -> row
    // seg*16 + (lane>>2), global 16B chunk pre-swizzled (lane&3)^((lane>>3)&3)
    int srow   = lane >> 2;
    int schunk = (((lane & 3) ^ ((lane >> 3) & 3)) << 4);
    const char* Ab0 = (const char*)(A + (size_t)(m0 + wave * 16 + srow) * KDIM) + schunk;
    const char* Ab1 = (const char*)(A + (size_t)(m0 + (wave + 4) * 16 + srow) * KDIM) + schunk;

    // B reg staging: thread t covers LDS row (t>>1) of panel 0 and panel 1,
    // 16 fp32 each at k-offset (t&1)*16
    int brow = tid >> 1;
    const float* Bg0 = We + (size_t)(n0 + brow) * KDIM + (tid & 1) * 16;
    const float* Bg1 = We + (size_t)(n0 + 128 + brow) * KDIM + (tid & 1) * 16;
    // slot for first 16B chunk; (brow+128)>>1 & 3 == brow>>1 & 3, same pattern
    int bslot0 = ((tid & 1) * 2) ^ ((brow >> 1) & 3);

    float4 bq[8];   // panel0: 0..3, panel1: 4..7

    int kf0 = kc * KCHUNK;   // element offset of this K chunk

#define STAGE_A(buf, kbyte) do {                                        \
        async_copy16(Ab0 + (kbyte), (char*)As[buf] + wave * 1024);      \
        async_copy16(Ab1 + (kbyte), (char*)As[buf] + (wave + 4) * 1024);\
    } while (0)

#define LOAD_B(kf) do {                                                 \
        const float* p0_ = Bg0 + (kf);                                  \
        const float* p1_ = Bg1 + (kf);                                  \
        bq[0] = *(const float4*)(p0_);      bq[1] = *(const float4*)(p0_ + 4);  \
        bq[2] = *(const float4*)(p0_ + 8);  bq[3] = *(const float4*)(p0_ + 12); \
        bq[4] = *(const float4*)(p1_);      bq[5] = *(const float4*)(p1_ + 4);  \
        bq[6] = *(const float4*)(p1_ + 8);  bq[7] = *(const float4*)(p1_ + 12); \
    } while (0)

#define WRITE_B(buf) do {                                               \
        uint4 q0_, q1_, q2_, q3_;                                       \
        q0_.x = pack2(bq[0].x, bq[0].y); q0_.y = pack2(bq[0].z, bq[0].w); \
        q0_.z = pack2(bq[1].x, bq[1].y); q0_.w = pack2(bq[1].z, bq[1].w); \
        q1_.x = pack2(bq[2].x, bq[2].y); q1_.y = pack2(bq[2].z, bq[2].w); \
        q1_.z = pack2(bq[3].x, bq[3].y); q1_.w = pack2(bq[3].z, bq[3].w); \
        q2_.x = pack2(bq[4].x, bq[4].y); q2_.y = pack2(bq[4].z, bq[4].w); \
        q2_.z = pack2(bq[5].x, bq[5].y); q2_.w = pack2(bq[5].z, bq[5].w); \
        q3_.x = pack2(bq[6].x, bq[6].y); q3_.y = pack2(bq[6].z, bq[6].w); \
        q3_.z = pack2(bq[7].x, bq[7].y); q3_.w = pack2(bq[7].z, bq[7].w); \
        char* bw0_ = (char*)Bs[buf] + brow * 64;                        \
        char* bw1_ = (char*)Bs[buf] + (128 + brow) * 64;                \
        *(uint4*)(bw0_ + bslot0 * 16)       = q0_;                      \
        *(uint4*)(bw0_ + (bslot0 ^ 1) * 16) = q1_;                      \
        *(uint4*)(bw1_ + bslot0 * 16)       = q2_;                      \
        *(uint4*)(bw1_ + (bslot0 ^ 1) * 16) = q3_;                      \
    } while (0)

    // prologue: stage tile 0 into buffer 0
    LOAD_B(kf0);
    STAGE_A(0, kf0 * 2);
    WRITE_B(0);
    __syncthreads();   // drains vmcnt (A DMA) + lgkm (B writes)

    // fragment read: row r, global chunk (lane>>4) -> LDS slot
    // (lane>>4) ^ ((r>>1)&3); bits 1-2 of r equal bits 1-2 of lane.
    int rchunk = (((lane >> 4) ^ ((lane >> 1) & 3)) << 4);

    for (int t = 0; t < NSTEP; ++t) {
        int cur = t & 1;
        bool pf = (t + 1 < NSTEP);
        if (pf) {                                  // issue-early
            int kf = kf0 + (t + 1) * 32;
            LOAD_B(kf);
            STAGE_A(cur ^ 1, kf * 2);
        }

        const char* as_c = (const char*)As[cur];
        const char* bs_c = (const char*)Bs[cur];
        bf16x8 af[4];
#pragma unroll
        for (int mi = 0; mi < 4; mi++) {
            int r = m_off + mi * 16 + (lane & 15);
            af[mi] = *(const bf16x8*)(as_c + r * 64 + rchunk);
        }
        // two ni-halves of 4 fragments each (caps live bfr registers)
#pragma unroll
        for (int h = 0; h < 2; h++) {
            bf16x8 bfr[4];
#pragma unroll
            for (int ni = 0; ni < 4; ni++) {
                int r = n_off + (h * 4 + ni) * 16 + (lane & 15);
                bfr[ni] = *(const bf16x8*)(bs_c + r * 64 + rchunk);
            }
#pragma unroll
            for (int mi = 0; mi < 4; mi++)
#pragma unroll
                for (int ni = 0; ni < 4; ni++)
                    acc[mi][h * 4 + ni] = __builtin_amdgcn_mfma_f32_16x16x32_bf16(
                        af[mi], bfr[ni], acc[mi][h * 4 + ni], 0, 0, 0);
        }

        if (pf) WRITE_B(cur ^ 1);                  // write-late
        __syncthreads();   // next buffer ready; all reads of cur done
    }
#undef STAGE_A
#undef LOAD_B
#undef WRITE_B

    // epilogue: C/D map col=lane&15, row=(lane>>4)*4+r
#pragma unroll
    for (int ni = 0; ni < 8; ni++) {
        int col = n0 + n_off + ni * 16 + (lane & 15);
        float bv = (OUT_MODE == 3) ? 0.f : bias[(size_t)e * NDIM + col];
#pragma unroll
        for (int mi = 0; mi < 4; mi++) {
            int row = m0 + m_off + mi * 16 + ((lane >> 4) * 4);
#pragma unroll
            for (int r2 = 0; r2 < 4; r2++) {
                float v = acc[mi][ni][r2] + bv;
                if (RELU) v = fmaxf(v, 0.f);
                if (OUT_MODE == 1)
                    ((unsigned short*)Out)[(size_t)(row + r2) * NDIM + col] = f2bf(v);
                else if (OUT_MODE == 0)
                    ((float*)Out)[(size_t)(row + r2) * NDIM + col] = v;
                else {  // 3: fp32 partial store, no atomics
                    float* o = (kc == 0) ? (float*)Out : (float*)Out2;
                    o[(size_t)(row + r2) * NDIM + col] = v;
                }
            }
        }
    }
}

// ---------------- combine: out[t] = sum_k w_k * (sum_parts Y[s_k] + b2[e_k])
__global__ __launch_bounds__(256) void combine_kernel(
    const float* __restrict__ Y0, const float* __restrict__ Y1,
    const int* __restrict__ slot_of, const int* __restrict__ topi,
    const float* __restrict__ topw, const float* __restrict__ b2,
    float* __restrict__ out)
{
    int t = blockIdx.x;
    int s0 = slot_of[t * 2], s1 = slot_of[t * 2 + 1];
    int e0 = topi[t * 2],    e1 = topi[t * 2 + 1];
    float w0 = topw[t * 2],  w1 = topw[t * 2 + 1];
    int i = threadIdx.x;
    float4 y0 = *(const float4*)(Y0 + (size_t)s0 * D_OUT + i * 4);
    float4 y1 = *(const float4*)(Y0 + (size_t)s1 * D_OUT + i * 4);
    if (Y1) {
        float4 a0 = *(const float4*)(Y1 + (size_t)s0 * D_OUT + i * 4);
        float4 a1 = *(const float4*)(Y1 + (size_t)s1 * D_OUT + i * 4);
        y0.x += a0.x; y0.y += a0.y; y0.z += a0.z; y0.w += a0.w;
        y1.x += a1.x; y1.y += a1.y; y1.z += a1.z; y1.w += a1.w;
    }
    float4 c0 = *(const float4*)(b2 + (size_t)e0 * D_OUT + i * 4);
    float4 c1 = *(const float4*)(b2 + (size_t)e1 * D_OUT + i * 4);
    float4 o;
    o.x = w0 * (y0.x + c0.x) + w1 * (y1.x + c1.x);
    o.y = w0 * (y0.y + c0.y) + w1 * (y1.y + c1.y);
    o.z = w0 * (y0.z + c0.z) + w1 * (y1.z + c1.z);
    o.w = w0 * (y0.w + c0.w) + w1 * (y1.w + c1.w);
    *(float4*)(out + (size_t)t * D_OUT + i * 4) = o;
}

extern "C" void kernel_launch(void* const* d_in, const int* in_sizes, int n_in,
                              void* d_out, int out_size, void* d_ws, size_t ws_size,
                              hipStream_t stream)
{
    const float* x  = (const float*)d_in[0];
    const float* gw = (const float*)d_in[1];
    const float* gb = (const float*)d_in[2];
    const float* W1 = (const float*)d_in[3];
    const float* b1 = (const float*)d_in[4];
    const float* W2 = (const float*)d_in[5];
    const float* b2 = (const float*)d_in[6];
    float* out = (float*)d_out;

    char* ws = (char*)d_ws;
    int* counts  = (int*)ws;                 // 8 ints
    int* cursor  = counts + 8;               // 8 ints
    int* offsets = counts + 16;              // 8 ints
    int* topi    = counts + 32;              // 4096 ints
    int* slot_of = counts + 32 + 4096;       // 4096 ints
    float* topw  = (float*)(counts + 32 + 8192);  // 4096 floats

    const size_t XE_OFF = 1ull << 16;
    const size_t H_OFF  = XE_OFF + (size_t)ROW_CAP * D_IN  * 2;  // +10.5 MB
    const size_t Y_OFF  = H_OFF  + (size_t)ROW_CAP * D_HID * 2;  // +41.9 MB
    const size_t Y1_OFF = Y_OFF  + (size_t)ROW_CAP * D_OUT * 4;  // +21.0 MB
    unsigned short* Xe = (unsigned short*)(ws + XE_OFF);
    unsigned short* H  = (unsigned short*)(ws + H_OFF);
    float*          Y  = (float*)(ws + Y_OFF);

    // second split-K partial; fall back to split-K=1 if workspace is small
    bool split2 = ws_size >= Y1_OFF + (size_t)ROW_CAP * D_OUT * 4;
    float* Y1 = split2 ? (float*)(ws + Y1_OFF) : nullptr;

    hipMemsetAsync(d_ws, 0, 128, stream);    // counts + cursor only

    gate_kernel<<<N_TOK / 4, 256, 0, stream>>>(x, gw, gb, topi, topw, counts);
    scan_kernel<<<1, 64, 0, stream>>>(counts, offsets, cursor);
    gather_kernel<<<N_TOK * TOPK, 64, 0, stream>>>(x, topi, cursor, slot_of, Xe);

    // GEMM1: H = relu(Xe @ W1^T + b1), bf16 out; W1 consumed as fp32
    moe_gemm<D_IN, D_HID, 1, true, 1><<<dim3(D_HID / 256, 16, NEXP), 256, 0, stream>>>(
        Xe, W1, b1, (void*)H, nullptr, counts, offsets);

    // GEMM2: Y(+Y1) = H @ W2^T partials (b2 folded into combine)
    if (split2) {
        moe_gemm<D_HID, D_OUT, 2, false, 3><<<dim3(D_OUT / 256, 16, NEXP * 2), 256, 0, stream>>>(
            H, W2, b2, (void*)Y, (void*)Y1, counts, offsets);
    } else {
        moe_gemm<D_HID, D_OUT, 1, false, 3><<<dim3(D_OUT / 256, 16, NEXP), 256, 0, stream>>>(
            H, W2, b2, (void*)Y, nullptr, counts, offsets);
    }

    combine_kernel<<<N_TOK, 256, 0, stream>>>(Y, Y1, slot_of, topi, topw, b2, out);
}

// Round 5
// 613.175 us; speedup vs baseline: 1.0554x; 1.0554x over previous
//
#include <hip/hip_runtime.h>
#include <hip/hip_bf16.h>

// SparseMoE: N=2048, D_IN=1024, D_HID=4096, D_OUT=1024, E=8, K=2.
// R7: revert to the R4 skeleton (best measured: 557 us total, GEMM 133 us;
// R5/R6 both regressed via VGPR bloat -> 2 waves/SIMD). Single change: the
// K-loop barrier. R4's __syncthreads drained vmcnt(0) every step, serially
// exposing HBM latency of the fp32 B-loads issued the same step. Now:
//  - B-loads issued 2 K-steps ahead into two NAMED reg sets (bqA/bqB,
//    static indexing), consumed by WRITE_B one full K-step after issue
//    (compiler's automatic dependence-waitcnt covers that use).
//  - barrier = "s_waitcnt vmcnt(4) lgkmcnt(0)" + raw s_barrier: retires the
//    2 A-DMA (needed next step), leaves the 4 B(t+2) loads in flight ACROSS
//    the barrier (AITER never-drain-0 pattern). vmcnt(0) only in the tail.
//  - exactly ONE sched_barrier(0) per step (pins A-DMA before B-load issue
//    so the count is well-defined); no other pinning (m141 lesson).
// Everything else (swizzle, fragment path, epilogue, small kernels, split-K2
// fp32 partial stores) identical to R4.

#define N_TOK   2048
#define D_IN    1024
#define D_HID   4096
#define D_OUT   1024
#define NEXP    8
#define TOPK    2
#define ROW_CAP 5120   // max padded rows: 4096 + 8*127 = 5112, round up

typedef __bf16 bf16x8 __attribute__((ext_vector_type(8)));
typedef float  f32x4  __attribute__((ext_vector_type(4)));

// native RNE casts; compiler emits v_cvt_pk_bf16_f32
__device__ inline unsigned short f2bf(float f) {
    return __builtin_bit_cast(unsigned short, (__bf16)f);
}
__device__ inline unsigned pack2(float lo, float hi) {
    unsigned short ua = __builtin_bit_cast(unsigned short, (__bf16)lo);
    unsigned short ub = __builtin_bit_cast(unsigned short, (__bf16)hi);
    return (unsigned)ua | ((unsigned)ub << 16);
}
__device__ inline void async_copy16(const void* g, void* l) {
    __builtin_amdgcn_global_load_lds(
        (const __attribute__((address_space(1))) void*)g,
        (__attribute__((address_space(3))) void*)l, 16, 0, 0);
}

// ---------------- gate: 1 wave per token ----------------
__global__ __launch_bounds__(256) void gate_kernel(
    const float* __restrict__ x, const float* __restrict__ gw,
    const float* __restrict__ gb, int* __restrict__ topi,
    float* __restrict__ topw, int* __restrict__ counts)
{
    int wave = threadIdx.x >> 6, lane = threadIdx.x & 63;
    int t = blockIdx.x * 4 + wave;
    const float* xt = x + (size_t)t * D_IN;
    float acc[NEXP];
#pragma unroll
    for (int e = 0; e < NEXP; e++) acc[e] = 0.f;
    for (int i = 0; i < D_IN / 64; i++) {
        float xv = xt[lane + 64 * i];
#pragma unroll
        for (int e = 0; e < NEXP; e++)
            acc[e] += xv * gw[e * D_IN + lane + 64 * i];
    }
#pragma unroll
    for (int e = 0; e < NEXP; e++) {
        float v = acc[e];
#pragma unroll
        for (int m = 32; m; m >>= 1) v += __shfl_xor(v, m, 64);
        acc[e] = v + gb[e];
    }
    if (lane == 0) {
        float b1v = -1e30f; int i1 = 0;
#pragma unroll
        for (int e = 0; e < NEXP; e++) if (acc[e] > b1v) { b1v = acc[e]; i1 = e; }
        float b2v = -1e30f; int i2 = 0;
#pragma unroll
        for (int e = 0; e < NEXP; e++) if (e != i1 && acc[e] > b2v) { b2v = acc[e]; i2 = e; }
        float e2 = __expf(b2v - b1v);
        float inv = 1.f / (1.f + e2);
        topi[t * 2] = i1; topi[t * 2 + 1] = i2;
        topw[t * 2] = inv; topw[t * 2 + 1] = e2 * inv;
        atomicAdd(&counts[i1], 1);
        atomicAdd(&counts[i2], 1);
    }
}

// ---------------- scan: 128-padded exclusive prefix ----------------
__global__ void scan_kernel(const int* __restrict__ counts,
                            int* __restrict__ offsets, int* __restrict__ cursor)
{
    if (threadIdx.x == 0 && blockIdx.x == 0) {
        int off = 0;
        for (int e = 0; e < NEXP; e++) {
            offsets[e] = off;
            cursor[e]  = off;
            off += (counts[e] + 127) & ~127;
        }
    }
}

// ---------------- gather: one wave per (token, k) slot ----------------
__global__ __launch_bounds__(64) void gather_kernel(
    const float* __restrict__ x, const int* __restrict__ topi,
    int* __restrict__ cursor, int* __restrict__ slot_of,
    unsigned short* __restrict__ Xe)
{
    int b = blockIdx.x;          // 0..N*TOPK-1
    int t = b >> 1;
    __shared__ int spos;
    if (threadIdx.x == 0) {
        int e = topi[b];
        int pos = atomicAdd(&cursor[e], 1);
        slot_of[b] = pos;
        spos = pos;
    }
    __syncthreads();
    int pos = spos;
    const float* src = x + (size_t)t * D_IN;
    unsigned short* dst = Xe + (size_t)pos * D_IN;
    int l = threadIdx.x;
#pragma unroll
    for (int i = 0; i < 4; i++) {
        float4 f = *(const float4*)(src + l * 4 + i * 256);
        uint2 p; p.x = pack2(f.x, f.y); p.y = pack2(f.z, f.w);
        *(uint2*)(dst + l * 4 + i * 256) = p;
    }
}

// ---------------- grouped GEMM (bf16 MFMA, fp32 weights, T4-lite) ----------
// Tile 128x128, BK=32, 4 waves x (4x4) 16x16x32 MFMA.
// A: [rows, KDIM] bf16, async global_load_lds 1 step ahead (pre-swizzled
//    global chunk, linear LDS dest).
// Wf: [E, NDIM, KDIM] fp32, register-staged 2 steps ahead (sets bqA/bqB),
//    cvt_pk->bf16 + ds_write into XOR-swizzled slots 1 step ahead.
// LDS: As 2x8KB + Bs 2x8KB = 32 KB. Swizzle: 64B row = 4x16B chunks,
// slot = chunk ^ ((row>>1)&3); fragment ds_read_b128 is 2-way (free).
// Barrier: s_waitcnt vmcnt(4) lgkmcnt(0); s_barrier -- A-DMA retired, the
// 4 B(t+2) loads stay in flight across the barrier.
// OUT_MODE: 1 = bf16 store (+bias, RELU), 3 = fp32 partial store
//   (kc==0 -> Out, kc==1 -> Out2), no bias.
template <int KDIM, int NDIM, int SPLITK, bool RELU, int OUT_MODE>
__global__ __launch_bounds__(256) void moe_gemm(
    const unsigned short* __restrict__ A, const float* __restrict__ Wf,
    const float* __restrict__ bias, void* __restrict__ Out, void* __restrict__ Out2,
    const int* __restrict__ counts, const int* __restrict__ offsets)
{
    constexpr int KCHUNK = KDIM / SPLITK;
    constexpr int NSTEP  = KCHUNK / 32;   // 32/64/128 -- always even
    int e  = blockIdx.z / SPLITK;
    int kc = blockIdx.z % SPLITK;
    int cnt = counts[e];
    int tm = blockIdx.y;
    if (tm * 128 >= cnt) return;
    int m0 = offsets[e] + tm * 128;
    int n0 = blockIdx.x * 128;

    __shared__ __align__(16) unsigned short As[2][128 * 32];
    __shared__ __align__(16) unsigned short Bs[2][128 * 32];

    int tid = threadIdx.x;
    int wave = tid >> 6, lane = tid & 63;

    const float* We = Wf + (size_t)e * NDIM * KDIM;

    f32x4 acc[4][4];
#pragma unroll
    for (int i = 0; i < 4; i++)
#pragma unroll
        for (int j = 0; j < 4; j++) acc[i][j] = (f32x4){0.f, 0.f, 0.f, 0.f};

    int m_off = (wave & 1) * 64;
    int n_off = (wave >> 1) * 64;

    // A staging (async DMA): segment s covers rows 16s..16s+15; lane -> row
    // seg*16 + (lane>>2), global 16B chunk pre-swizzled (lane&3)^((lane>>3)&3)
    int srow   = lane >> 2;
    int schunk = (((lane & 3) ^ ((lane >> 3) & 3)) << 4);
    const char* Ab0 = (const char*)(A + (size_t)(m0 + wave * 16 + srow) * KDIM) + schunk;
    const char* Ab1 = (const char*)(A + (size_t)(m0 + (wave + 4) * 16 + srow) * KDIM) + schunk;

    // B reg staging: thread t covers row t>>1, 16 fp32 at k-offset (t&1)*16
    int brow = tid >> 1;
    const float* Bg = We + (size_t)(n0 + brow) * KDIM + (tid & 1) * 16;
    int bslot0 = ((tid & 1) * 2) ^ ((brow >> 1) & 3);   // second slot = ^1

    float4 bqA[4], bqB[4];   // two K-step-parity register sets (static idx)

    int kf0 = kc * KCHUNK;   // element offset of this K chunk

#define STAGE_A(buf, kbyte) do {                                        \
        async_copy16(Ab0 + (kbyte), (char*)As[buf] + wave * 1024);      \
        async_copy16(Ab1 + (kbyte), (char*)As[buf] + (wave + 4) * 1024);\
    } while (0)

#define LOAD_B_TO(dst, step) do {                                       \
        const float* p_ = Bg + (kf0 + (step) * 32);                     \
        dst[0] = *(const float4*)(p_);                                  \
        dst[1] = *(const float4*)(p_ + 4);                              \
        dst[2] = *(const float4*)(p_ + 8);                              \
        dst[3] = *(const float4*)(p_ + 12);                             \
    } while (0)

#define WRITE_B_FROM(src, buf) do {                                     \
        uint4 q0_, q1_;                                                 \
        q0_.x = pack2(src[0].x, src[0].y); q0_.y = pack2(src[0].z, src[0].w); \
        q0_.z = pack2(src[1].x, src[1].y); q0_.w = pack2(src[1].z, src[1].w); \
        q1_.x = pack2(src[2].x, src[2].y); q1_.y = pack2(src[2].z, src[2].w); \
        q1_.z = pack2(src[3].x, src[3].y); q1_.w = pack2(src[3].z, src[3].w); \
        char* bw_ = (char*)Bs[buf] + brow * 64;                         \
        *(uint4*)(bw_ + bslot0 * 16)       = q0_;                       \
        *(uint4*)(bw_ + (bslot0 ^ 1) * 16) = q1_;                       \
    } while (0)

    // fragment read: row r, global chunk (lane>>4) -> LDS slot
    // (lane>>4) ^ ((r>>1)&3); bits 1-2 of r equal bits 1-2 of lane.
    int rchunk = (((lane >> 4) ^ ((lane >> 1) & 3)) << 4);

    // -------- prologue --------
    // issue order: A(0) DMA x2, then B(0) x4, B(1) x4. WRITE_B(bqA) dep-waits
    // B(0) (auto vmcnt(4)), which also retires the older A(0).
    STAGE_A(0, kf0 * 2);
    __builtin_amdgcn_sched_barrier(0);
    LOAD_B_TO(bqA, 0);
    LOAD_B_TO(bqB, 1);
    WRITE_B_FROM(bqA, 0);
    asm volatile("s_waitcnt vmcnt(4) lgkmcnt(0)" ::: "memory");
    __builtin_amdgcn_s_barrier();

    // -------- steady state --------
    // step T (parity CUR): issue A(T+1) DMA, [sched_barrier], issue B(T+2)
    // into LDSET; compute buf[CUR]; WRITE_B from WRSET (loaded at T-1) into
    // buf[CUR^1]; wait vmcnt(4) lgkm(0); s_barrier.
#define KSTEP(T, CUR, LDSET, WRSET) do {                                     \
        if ((T) + 1 < NSTEP) STAGE_A((CUR) ^ 1, (kf0 + ((T) + 1) * 32) * 2); \
        __builtin_amdgcn_sched_barrier(0);                                   \
        if ((T) + 2 < NSTEP) LOAD_B_TO(LDSET, (T) + 2);                      \
        {                                                                    \
            const char* as_c = (const char*)As[CUR];                         \
            const char* bs_c = (const char*)Bs[CUR];                         \
            bf16x8 af[4], bfr[4];                                            \
            _Pragma("unroll")                                                \
            for (int mi = 0; mi < 4; mi++) {                                 \
                int r = m_off + mi * 16 + (lane & 15);                       \
                af[mi] = *(const bf16x8*)(as_c + r * 64 + rchunk);           \
            }                                                                \
            _Pragma("unroll")                                                \
            for (int ni = 0; ni < 4; ni++) {                                 \
                int r = n_off + ni * 16 + (lane & 15);                       \
                bfr[ni] = *(const bf16x8*)(bs_c + r * 64 + rchunk);          \
            }                                                                \
            _Pragma("unroll")                                                \
            for (int mi = 0; mi < 4; mi++)                                   \
                _Pragma("unroll")                                            \
                for (int ni = 0; ni < 4; ni++)                               \
                    acc[mi][ni] = __builtin_amdgcn_mfma_f32_16x16x32_bf16(   \
                        af[mi], bfr[ni], acc[mi][ni], 0, 0, 0);              \
        }                                                                    \
        if ((T) + 1 < NSTEP) WRITE_B_FROM(WRSET, (CUR) ^ 1);                 \
        if ((T) + 2 < NSTEP) {                                               \
            asm volatile("s_waitcnt vmcnt(4) lgkmcnt(0)" ::: "memory");      \
        } else {                                                             \
            asm volatile("s_waitcnt vmcnt(0) lgkmcnt(0)" ::: "memory");      \
        }                                                                    \
        __builtin_amdgcn_s_barrier();                                        \
    } while (0)

    for (int t = 0; t < NSTEP; t += 2) {
        KSTEP(t,     0, bqA, bqB);   // load B(t+2)->bqA, write B(t+1) from bqB
        KSTEP(t + 1, 1, bqB, bqA);   // load B(t+3)->bqB, write B(t+2) from bqA
    }
#undef KSTEP
#undef STAGE_A
#undef LOAD_B_TO
#undef WRITE_B_FROM

    // epilogue: C/D map col=lane&15, row=(lane>>4)*4+r
#pragma unroll
    for (int ni = 0; ni < 4; ni++) {
        int col = n0 + n_off + ni * 16 + (lane & 15);
        float bv = (OUT_MODE == 3) ? 0.f : bias[(size_t)e * NDIM + col];
#pragma unroll
        for (int mi = 0; mi < 4; mi++) {
            int row = m0 + m_off + mi * 16 + ((lane >> 4) * 4);
#pragma unroll
            for (int r2 = 0; r2 < 4; r2++) {
                float v = acc[mi][ni][r2] + bv;
                if (RELU) v = fmaxf(v, 0.f);
                if (OUT_MODE == 1)
                    ((unsigned short*)Out)[(size_t)(row + r2) * NDIM + col] = f2bf(v);
                else if (OUT_MODE == 0)
                    ((float*)Out)[(size_t)(row + r2) * NDIM + col] = v;
                else {  // 3: fp32 partial store, no atomics
                    float* o = (kc == 0) ? (float*)Out : (float*)Out2;
                    o[(size_t)(row + r2) * NDIM + col] = v;
                }
            }
        }
    }
}

// ---------------- combine: out[t] = sum_k w_k * (sum_parts Y[s_k] + b2[e_k])
__global__ __launch_bounds__(256) void combine_kernel(
    const float* __restrict__ Y0, const float* __restrict__ Y1,
    const int* __restrict__ slot_of, const int* __restrict__ topi,
    const float* __restrict__ topw, const float* __restrict__ b2,
    float* __restrict__ out)
{
    int t = blockIdx.x;
    int s0 = slot_of[t * 2], s1 = slot_of[t * 2 + 1];
    int e0 = topi[t * 2],    e1 = topi[t * 2 + 1];
    float w0 = topw[t * 2],  w1 = topw[t * 2 + 1];
    int i = threadIdx.x;
    float4 y0 = *(const float4*)(Y0 + (size_t)s0 * D_OUT + i * 4);
    float4 y1 = *(const float4*)(Y0 + (size_t)s1 * D_OUT + i * 4);
    if (Y1) {
        float4 a0 = *(const float4*)(Y1 + (size_t)s0 * D_OUT + i * 4);
        float4 a1 = *(const float4*)(Y1 + (size_t)s1 * D_OUT + i * 4);
        y0.x += a0.x; y0.y += a0.y; y0.z += a0.z; y0.w += a0.w;
        y1.x += a1.x; y1.y += a1.y; y1.z += a1.z; y1.w += a1.w;
    }
    float4 c0 = *(const float4*)(b2 + (size_t)e0 * D_OUT + i * 4);
    float4 c1 = *(const float4*)(b2 + (size_t)e1 * D_OUT + i * 4);
    float4 o;
    o.x = w0 * (y0.x + c0.x) + w1 * (y1.x + c1.x);
    o.y = w0 * (y0.y + c0.y) + w1 * (y1.y + c1.y);
    o.z = w0 * (y0.z + c0.z) + w1 * (y1.z + c1.z);
    o.w = w0 * (y0.w + c0.w) + w1 * (y1.w + c1.w);
    *(float4*)(out + (size_t)t * D_OUT + i * 4) = o;
}

extern "C" void kernel_launch(void* const* d_in, const int* in_sizes, int n_in,
                              void* d_out, int out_size, void* d_ws, size_t ws_size,
                              hipStream_t stream)
{
    const float* x  = (const float*)d_in[0];
    const float* gw = (const float*)d_in[1];
    const float* gb = (const float*)d_in[2];
    const float* W1 = (const float*)d_in[3];
    const float* b1 = (const float*)d_in[4];
    const float* W2 = (const float*)d_in[5];
    const float* b2 = (const float*)d_in[6];
    float* out = (float*)d_out;

    char* ws = (char*)d_ws;
    int* counts  = (int*)ws;                 // 8 ints
    int* cursor  = counts + 8;               // 8 ints
    int* offsets = counts + 16;              // 8 ints
    int* topi    = counts + 32;              // 4096 ints
    int* slot_of = counts + 32 + 4096;       // 4096 ints
    float* topw  = (float*)(counts + 32 + 8192);  // 4096 floats

    const size_t XE_OFF = 1ull << 16;
    const size_t H_OFF  = XE_OFF + (size_t)ROW_CAP * D_IN  * 2;  // +10.5 MB
    const size_t Y_OFF  = H_OFF  + (size_t)ROW_CAP * D_HID * 2;  // +41.9 MB
    const size_t Y1_OFF = Y_OFF  + (size_t)ROW_CAP * D_OUT * 4;  // +21.0 MB
    unsigned short* Xe = (unsigned short*)(ws + XE_OFF);
    unsigned short* H  = (unsigned short*)(ws + H_OFF);
    float*          Y  = (float*)(ws + Y_OFF);

    // second split-K partial; fall back to split-K=1 if workspace is small
    bool split2 = ws_size >= Y1_OFF + (size_t)ROW_CAP * D_OUT * 4;
    float* Y1 = split2 ? (float*)(ws + Y1_OFF) : nullptr;

    hipMemsetAsync(d_ws, 0, 128, stream);    // counts + cursor only

    gate_kernel<<<N_TOK / 4, 256, 0, stream>>>(x, gw, gb, topi, topw, counts);
    scan_kernel<<<1, 64, 0, stream>>>(counts, offsets, cursor);
    gather_kernel<<<N_TOK * TOPK, 64, 0, stream>>>(x, topi, cursor, slot_of, Xe);

    // GEMM1: H = relu(Xe @ W1^T + b1), bf16 out; W1 consumed as fp32
    moe_gemm<D_IN, D_HID, 1, true, 1><<<dim3(D_HID / 128, 16, NEXP), 256, 0, stream>>>(
        Xe, W1, b1, (void*)H, nullptr, counts, offsets);

    // GEMM2: Y(+Y1) = H @ W2^T partials (b2 folded into combine)
    if (split2) {
        moe_gemm<D_HID, D_OUT, 2, false, 3><<<dim3(D_OUT / 128, 16, NEXP * 2), 256, 0, stream>>>(
            H, W2, b2, (void*)Y, (void*)Y1, counts, offsets);
    } else {
        moe_gemm<D_HID, D_OUT, 1, false, 3><<<dim3(D_OUT / 128, 16, NEXP), 256, 0, stream>>>(
            H, W2, b2, (void*)Y, nullptr, counts, offsets);
    }

    combine_kernel<<<N_TOK, 256, 0, stream>>>(Y, Y1, slot_of, topi, topw, b2, out);
}

// Round 6
// 534.779 us; speedup vs baseline: 1.2101x; 1.1466x over previous
//
#include <hip/hip_runtime.h>
#include <hip/hip_bf16.h>

// SparseMoE: N=2048, D_IN=1024, D_HID=4096, D_OUT=1024, E=8, K=2.
// R8: abandon the counted-vmcnt arc (R5/R6/R7 all regressed -- T4 needs the
// full 8-phase schedule, not a 2-phase graft; catalog regime-gate confirmed
// thrice). Return to the best-measured per-GEMM structure: R3's all-bf16
// loop (A and B both staged via global_load_lds, XOR swizzle, 2-phase
// __syncthreads dbuf; both GEMMs < 115 us). Make the weight convert ~free:
//  - W1 fp32->bf16 convert blocks FUSED into the gate launch (independent
//    work, grid-partitioned; 16B stores instead of R3's 8B).
//  - W2 convert blocks FUSED into the GEMM1 launch as blockIdx.z==NEXP
//    (GEMM1 is latency-bound at ~1.7 TB/s -- spare BW absorbs the 201 MB).
//  - stream order guarantees W2b ready before GEMM2.
// GEMM2 keeps split-K=2 with plain fp32 partial stores summed in combine.

#define N_TOK   2048
#define D_IN    1024
#define D_HID   4096
#define D_OUT   1024
#define NEXP    8
#define TOPK    2
#define ROW_CAP 5120   // max padded rows: 4096 + 8*127 = 5112, round up

#define GATE_BLKS   (N_TOK / 4)     // 512
#define CONV1_BLKS  1024

typedef __bf16 bf16x8 __attribute__((ext_vector_type(8)));
typedef float  f32x4  __attribute__((ext_vector_type(4)));

// native RNE casts; compiler emits v_cvt_pk_bf16_f32-class code
__device__ inline unsigned short f2bf(float f) {
    return __builtin_bit_cast(unsigned short, (__bf16)f);
}
__device__ inline unsigned pack2(float lo, float hi) {
    unsigned short ua = __builtin_bit_cast(unsigned short, (__bf16)lo);
    unsigned short ub = __builtin_bit_cast(unsigned short, (__bf16)hi);
    return (unsigned)ua | ((unsigned)ub << 16);
}
__device__ inline void async_copy16(const void* g, void* l) {
    __builtin_amdgcn_global_load_lds(
        (const __attribute__((address_space(1))) void*)g,
        (__attribute__((address_space(3))) void*)l, 16, 0, 0);
}

// convert helper: i-th 16B output = pack of 2 float4 (32B input)
__device__ inline void conv8(const float4* __restrict__ s,
                             uint4* __restrict__ d, int i)
{
    float4 a = s[2 * i], b = s[2 * i + 1];
    uint4 q;
    q.x = pack2(a.x, a.y); q.y = pack2(a.z, a.w);
    q.z = pack2(b.x, b.y); q.w = pack2(b.z, b.w);
    d[i] = q;
}

// ---------------- gate (blocks 0..511) + W1 convert (blocks 512..1535) -----
__global__ __launch_bounds__(256) void gate_conv1(
    const float* __restrict__ x, const float* __restrict__ gw,
    const float* __restrict__ gb, int* __restrict__ topi,
    float* __restrict__ topw, int* __restrict__ counts,
    const float4* __restrict__ w1_src, uint4* __restrict__ w1_dst, int n8)
{
    if (blockIdx.x >= GATE_BLKS) {
        int id = (blockIdx.x - GATE_BLKS) * 256 + threadIdx.x;
        int stride = CONV1_BLKS * 256;
        for (int i = id; i < n8; i += stride) conv8(w1_src, w1_dst, i);
        return;
    }
    int wave = threadIdx.x >> 6, lane = threadIdx.x & 63;
    int t = blockIdx.x * 4 + wave;
    const float* xt = x + (size_t)t * D_IN;
    float acc[NEXP];
#pragma unroll
    for (int e = 0; e < NEXP; e++) acc[e] = 0.f;
    for (int i = 0; i < D_IN / 64; i++) {
        float xv = xt[lane + 64 * i];
#pragma unroll
        for (int e = 0; e < NEXP; e++)
            acc[e] += xv * gw[e * D_IN + lane + 64 * i];
    }
#pragma unroll
    for (int e = 0; e < NEXP; e++) {
        float v = acc[e];
#pragma unroll
        for (int m = 32; m; m >>= 1) v += __shfl_xor(v, m, 64);
        acc[e] = v + gb[e];
    }
    if (lane == 0) {
        float b1v = -1e30f; int i1 = 0;
#pragma unroll
        for (int e = 0; e < NEXP; e++) if (acc[e] > b1v) { b1v = acc[e]; i1 = e; }
        float b2v = -1e30f; int i2 = 0;
#pragma unroll
        for (int e = 0; e < NEXP; e++) if (e != i1 && acc[e] > b2v) { b2v = acc[e]; i2 = e; }
        float e2 = __expf(b2v - b1v);
        float inv = 1.f / (1.f + e2);
        topi[t * 2] = i1; topi[t * 2 + 1] = i2;
        topw[t * 2] = inv; topw[t * 2 + 1] = e2 * inv;
        atomicAdd(&counts[i1], 1);
        atomicAdd(&counts[i2], 1);
    }
}

// ---------------- scan: 128-padded exclusive prefix ----------------
__global__ void scan_kernel(const int* __restrict__ counts,
                            int* __restrict__ offsets, int* __restrict__ cursor)
{
    if (threadIdx.x == 0 && blockIdx.x == 0) {
        int off = 0;
        for (int e = 0; e < NEXP; e++) {
            offsets[e] = off;
            cursor[e]  = off;
            off += (counts[e] + 127) & ~127;
        }
    }
}

// ---------------- gather: one wave per (token, k) slot ----------------
__global__ __launch_bounds__(64) void gather_kernel(
    const float* __restrict__ x, const int* __restrict__ topi,
    int* __restrict__ cursor, int* __restrict__ slot_of,
    unsigned short* __restrict__ Xe)
{
    int b = blockIdx.x;          // 0..N*TOPK-1
    int t = b >> 1;
    __shared__ int spos;
    if (threadIdx.x == 0) {
        int e = topi[b];
        int pos = atomicAdd(&cursor[e], 1);
        slot_of[b] = pos;
        spos = pos;
    }
    __syncthreads();
    int pos = spos;
    const float* src = x + (size_t)t * D_IN;
    unsigned short* dst = Xe + (size_t)pos * D_IN;
    int l = threadIdx.x;
#pragma unroll
    for (int i = 0; i < 4; i++) {
        float4 f = *(const float4*)(src + l * 4 + i * 256);
        uint2 p; p.x = pack2(f.x, f.y); p.y = pack2(f.z, f.w);
        *(uint2*)(dst + l * 4 + i * 256) = p;
    }
}

// ---------------- grouped GEMM (pure bf16, R3 structure) -------------------
// A: [rows, KDIM] bf16. Wb: [E, NDIM, KDIM] bf16. Tile 128x128, BK=32,
// 4 waves x (4x4) 16x16x32 MFMA, double-buffered LDS, one __syncthreads per
// K-step. LDS swizzle: 64B row = 4x16B chunks, slot = chunk ^ ((row>>1)&3);
// staging pre-permutes the GLOBAL source chunk (LDS dest of global_load_lds
// stays linear, rule 21); fragment ds_read_b128 is 2-way bank access (free).
// CONV: blockIdx.z == NEXP layer converts cw_n8 16B-groups fp32->bf16
// (W2 pre-conversion riding on GEMM1's spare HBM bandwidth).
// OUT_MODE: 1 = bf16 store (+bias, RELU), 3 = fp32 partial store
//   (kc==0 -> Out, kc==1 -> Out2), no bias.
template <int KDIM, int NDIM, int SPLITK, bool RELU, int OUT_MODE, bool CONV>
__global__ __launch_bounds__(256) void moe_gemm(
    const unsigned short* __restrict__ A, const unsigned short* __restrict__ Wb,
    const float* __restrict__ bias, void* __restrict__ Out, void* __restrict__ Out2,
    const int* __restrict__ counts, const int* __restrict__ offsets,
    const float4* __restrict__ cw_src, uint4* __restrict__ cw_dst, int cw_n8)
{
    if (CONV && blockIdx.z == NEXP * SPLITK) {
        int id = (blockIdx.y * gridDim.x + blockIdx.x) * 256 + threadIdx.x;
        int stride = gridDim.x * gridDim.y * 256;
        for (int i = id; i < cw_n8; i += stride) conv8(cw_src, cw_dst, i);
        return;
    }

    constexpr int KCHUNK = KDIM / SPLITK;
    constexpr int NSTEP  = KCHUNK / 32;
    int e  = blockIdx.z / SPLITK;
    int kc = blockIdx.z % SPLITK;
    int cnt = counts[e];
    int tm = blockIdx.y;
    if (tm * 128 >= cnt) return;
    int m0 = offsets[e] + tm * 128;
    int n0 = blockIdx.x * 128;

    __shared__ __align__(16) unsigned short As[2][128 * 32];
    __shared__ __align__(16) unsigned short Bs[2][128 * 32];

    int tid = threadIdx.x;
    int wave = tid >> 6, lane = tid & 63;

    const unsigned short* We = Wb + (size_t)e * NDIM * KDIM;

    f32x4 acc[4][4];
#pragma unroll
    for (int i = 0; i < 4; i++)
#pragma unroll
        for (int j = 0; j < 4; j++) acc[i][j] = (f32x4){0.f, 0.f, 0.f, 0.f};

    int m_off = (wave & 1) * 64;
    int n_off = (wave >> 1) * 64;

    // staging: segment s covers rows 16s..16s+15, LDS bytes [s*1024, +1024)
    // lane -> row = seg*16 + (lane>>2); global 16B chunk pre-swizzled:
    // (lane&3) ^ ((row>>1)&3) = (lane&3) ^ ((lane>>3)&3)
    int srow   = lane >> 2;
    int schunk = (((lane & 3) ^ ((lane >> 3) & 3)) << 4);

    const char* Ab0 = (const char*)(A  + (size_t)(m0 + wave * 16 + srow) * KDIM) + schunk;
    const char* Ab1 = (const char*)(A  + (size_t)(m0 + (wave + 4) * 16 + srow) * KDIM) + schunk;
    const char* Bb0 = (const char*)(We + (size_t)(n0 + wave * 16 + srow) * KDIM) + schunk;
    const char* Bb1 = (const char*)(We + (size_t)(n0 + (wave + 4) * 16 + srow) * KDIM) + schunk;

#define STAGE(buf, kbyte) do {                                          \
        async_copy16(Ab0 + (kbyte), (char*)As[buf] + wave * 1024);      \
        async_copy16(Ab1 + (kbyte), (char*)As[buf] + (wave + 4) * 1024);\
        async_copy16(Bb0 + (kbyte), (char*)Bs[buf] + wave * 1024);      \
        async_copy16(Bb1 + (kbyte), (char*)Bs[buf] + (wave + 4) * 1024);\
    } while (0)

    int kbyte0 = kc * KCHUNK * 2;
    STAGE(0, kbyte0);
    __syncthreads();   // drains vmcnt: buffer 0 ready

    // fragment read: row r, global chunk (lane>>4) -> LDS slot
    // (lane>>4) ^ ((r>>1)&3); bits 1-2 of r equal bits 1-2 of lane.
    int rchunk = (((lane >> 4) ^ ((lane >> 1) & 3)) << 4);

    for (int t = 0; t < NSTEP; ++t) {
        int cur = t & 1;
        if (t + 1 < NSTEP) STAGE(cur ^ 1, kbyte0 + (t + 1) * 64);  // prefetch

        const char* as_c = (const char*)As[cur];
        const char* bs_c = (const char*)Bs[cur];
        bf16x8 af[4], bfr[4];
#pragma unroll
        for (int mi = 0; mi < 4; mi++) {
            int r = m_off + mi * 16 + (lane & 15);
            af[mi] = *(const bf16x8*)(as_c + r * 64 + rchunk);
        }
#pragma unroll
        for (int ni = 0; ni < 4; ni++) {
            int r = n_off + ni * 16 + (lane & 15);
            bfr[ni] = *(const bf16x8*)(bs_c + r * 64 + rchunk);
        }
#pragma unroll
        for (int mi = 0; mi < 4; mi++)
#pragma unroll
            for (int ni = 0; ni < 4; ni++)
                acc[mi][ni] = __builtin_amdgcn_mfma_f32_16x16x32_bf16(
                    af[mi], bfr[ni], acc[mi][ni], 0, 0, 0);

        __syncthreads();   // drains vmcnt (prefetch) + all lgkm before reuse
    }
#undef STAGE

    // epilogue: C/D map col=lane&15, row=(lane>>4)*4+r
#pragma unroll
    for (int ni = 0; ni < 4; ni++) {
        int col = n0 + n_off + ni * 16 + (lane & 15);
        float bv = (OUT_MODE == 3) ? 0.f : bias[(size_t)e * NDIM + col];
#pragma unroll
        for (int mi = 0; mi < 4; mi++) {
            int row = m0 + m_off + mi * 16 + ((lane >> 4) * 4);
#pragma unroll
            for (int r2 = 0; r2 < 4; r2++) {
                float v = acc[mi][ni][r2] + bv;
                if (RELU) v = fmaxf(v, 0.f);
                if (OUT_MODE == 1)
                    ((unsigned short*)Out)[(size_t)(row + r2) * NDIM + col] = f2bf(v);
                else if (OUT_MODE == 0)
                    ((float*)Out)[(size_t)(row + r2) * NDIM + col] = v;
                else {  // 3: fp32 partial store, no atomics
                    float* o = (kc == 0) ? (float*)Out : (float*)Out2;
                    o[(size_t)(row + r2) * NDIM + col] = v;
                }
            }
        }
    }
}

// ---------------- combine: out[t] = sum_k w_k * (sum_parts Y[s_k] + b2[e_k])
__global__ __launch_bounds__(256) void combine_kernel(
    const float* __restrict__ Y0, const float* __restrict__ Y1,
    const int* __restrict__ slot_of, const int* __restrict__ topi,
    const float* __restrict__ topw, const float* __restrict__ b2,
    float* __restrict__ out)
{
    int t = blockIdx.x;
    int s0 = slot_of[t * 2], s1 = slot_of[t * 2 + 1];
    int e0 = topi[t * 2],    e1 = topi[t * 2 + 1];
    float w0 = topw[t * 2],  w1 = topw[t * 2 + 1];
    int i = threadIdx.x;
    float4 y0 = *(const float4*)(Y0 + (size_t)s0 * D_OUT + i * 4);
    float4 y1 = *(const float4*)(Y0 + (size_t)s1 * D_OUT + i * 4);
    if (Y1) {
        float4 a0 = *(const float4*)(Y1 + (size_t)s0 * D_OUT + i * 4);
        float4 a1 = *(const float4*)(Y1 + (size_t)s1 * D_OUT + i * 4);
        y0.x += a0.x; y0.y += a0.y; y0.z += a0.z; y0.w += a0.w;
        y1.x += a1.x; y1.y += a1.y; y1.z += a1.z; y1.w += a1.w;
    }
    float4 c0 = *(const float4*)(b2 + (size_t)e0 * D_OUT + i * 4);
    float4 c1 = *(const float4*)(b2 + (size_t)e1 * D_OUT + i * 4);
    float4 o;
    o.x = w0 * (y0.x + c0.x) + w1 * (y1.x + c1.x);
    o.y = w0 * (y0.y + c0.y) + w1 * (y1.y + c1.y);
    o.z = w0 * (y0.z + c0.z) + w1 * (y1.z + c1.z);
    o.w = w0 * (y0.w + c0.w) + w1 * (y1.w + c1.w);
    *(float4*)(out + (size_t)t * D_OUT + i * 4) = o;
}

extern "C" void kernel_launch(void* const* d_in, const int* in_sizes, int n_in,
                              void* d_out, int out_size, void* d_ws, size_t ws_size,
                              hipStream_t stream)
{
    const float* x  = (const float*)d_in[0];
    const float* gw = (const float*)d_in[1];
    const float* gb = (const float*)d_in[2];
    const float* W1 = (const float*)d_in[3];
    const float* b1 = (const float*)d_in[4];
    const float* W2 = (const float*)d_in[5];
    const float* b2 = (const float*)d_in[6];
    float* out = (float*)d_out;

    char* ws = (char*)d_ws;
    int* counts  = (int*)ws;                 // 8 ints
    int* cursor  = counts + 8;               // 8 ints
    int* offsets = counts + 16;              // 8 ints
    int* topi    = counts + 32;              // 4096 ints
    int* slot_of = counts + 32 + 4096;       // 4096 ints
    float* topw  = (float*)(counts + 32 + 8192);  // 4096 floats

    const size_t XE_OFF  = 1ull << 16;
    const size_t H_OFF   = XE_OFF  + (size_t)ROW_CAP * D_IN  * 2;      // +10.5 MB
    const size_t Y_OFF   = H_OFF   + (size_t)ROW_CAP * D_HID * 2;      // +41.9 MB
    const size_t W1B_OFF = Y_OFF   + (size_t)ROW_CAP * D_OUT * 4;      // +21.0 MB
    const size_t W2B_OFF = W1B_OFF + (size_t)NEXP * D_HID * D_IN * 2;  // +67.1 MB
    const size_t Y1_OFF  = W2B_OFF + (size_t)NEXP * D_OUT * D_HID * 2; // +67.1 MB
    unsigned short* Xe  = (unsigned short*)(ws + XE_OFF);
    unsigned short* H   = (unsigned short*)(ws + H_OFF);
    float*          Y   = (float*)(ws + Y_OFF);
    unsigned short* W1b = (unsigned short*)(ws + W1B_OFF);
    unsigned short* W2b = (unsigned short*)(ws + W2B_OFF);

    // second split-K partial at the tail; fall back to split-K=1 if small
    bool split2 = ws_size >= Y1_OFF + (size_t)ROW_CAP * D_OUT * 4;
    float* Y1 = split2 ? (float*)(ws + Y1_OFF) : nullptr;

    hipMemsetAsync(d_ws, 0, 128, stream);    // counts + cursor only

    const int W1_N8 = NEXP * D_HID * D_IN / 8;   // 16B output groups
    const int W2_N8 = NEXP * D_OUT * D_HID / 8;

    // gate (512 blocks) + W1 convert (1024 blocks), fused
    gate_conv1<<<GATE_BLKS + CONV1_BLKS, 256, 0, stream>>>(
        x, gw, gb, topi, topw, counts, (const float4*)W1, (uint4*)W1b, W1_N8);
    scan_kernel<<<1, 64, 0, stream>>>(counts, offsets, cursor);
    gather_kernel<<<N_TOK * TOPK, 64, 0, stream>>>(x, topi, cursor, slot_of, Xe);

    // GEMM1: H = relu(Xe @ W1b^T + b1), bf16 out; z==8 layer converts W2
    moe_gemm<D_IN, D_HID, 1, true, 1, true>
        <<<dim3(D_HID / 128, 16, NEXP + 1), 256, 0, stream>>>(
        Xe, W1b, b1, (void*)H, nullptr, counts, offsets,
        (const float4*)W2, (uint4*)W2b, W2_N8);

    // GEMM2: Y(+Y1) = H @ W2b^T partials (b2 folded into combine)
    if (split2) {
        moe_gemm<D_HID, D_OUT, 2, false, 3, false>
            <<<dim3(D_OUT / 128, 16, NEXP * 2), 256, 0, stream>>>(
            H, W2b, b2, (void*)Y, (void*)Y1, counts, offsets, nullptr, nullptr, 0);
    } else {
        moe_gemm<D_HID, D_OUT, 1, false, 3, false>
            <<<dim3(D_OUT / 128, 16, NEXP), 256, 0, stream>>>(
            H, W2b, b2, (void*)Y, nullptr, counts, offsets, nullptr, nullptr, 0);
    }

    combine_kernel<<<N_TOK, 256, 0, stream>>>(Y, Y1, slot_of, topi, topw, b2, out);
}